// Round 8
// baseline (256.588 us; speedup 1.0000x reference)
//
#include <hip/hip_runtime.h>
#include <hip/hip_bf16.h>
#include <math.h>

#define B_SZ   1024
#define NROW   2048      // 2B
#define D_K    16384     // 128*128
#define SPLIT  8
#define KSEG   (D_K / SPLIT)   // 2048
#define NTILE  16
#define NPAIR  136
#define NSUB   4               // loss sub-blocks per tile (rows/32)
#define NPT    (NPAIR * NSUB)  // 544
// fp8 rows scaled by 16 each => sim holds 256 * true_sim.
#define TEMP_SIM (2.0f / 256.0f)

typedef float f32x4 __attribute__((ext_vector_type(4)));
typedef long  i64;
typedef long  i64x2 __attribute__((ext_vector_type(2)));

typedef __attribute__((address_space(1))) unsigned int GU32;
typedef __attribute__((address_space(3))) unsigned int LU32;

__device__ __forceinline__ void async16(const void* g, void* l) {
  __builtin_amdgcn_global_load_lds((GU32*)(g), (LU32*)(l), 16, 0, 0);
}

// ---------------------------------------------------------------------------
// rn GLOBAL layout (verified zero-conflict r3/r5/r6): row r is split into 64B
// K-segments. Subchunk s (k-bytes [8s,8s+8)), q=s&3, h=s>>2 stored at byte
// (q ^ ((r>>1)&3))*16 + h*8. gemm stages each 64B segment as one LDS "plane"
// row (64B row stride); fragment read = ONE ds_read_b128 per (row, segment)
// at row*64 + (quad^((col>>1)&3))*16, halves = the two 32k MFMA operands.
// Measured SQ_LDS_BANK_CONFLICT == 0 with this pattern.
//
// Ledger of measured config deltas (rest = total - sum(gemm)):
//  - zero_sim as separate dispatch vs fused into norm: -8.6 us (r5 vs r6;
//    r6's comment claiming the opposite was an attribution error).
//  - gemm grid (SPLIT,NPAIR) vs (NPAIR,SPLIT): -8 us, FETCH 16.4 vs 152 MB
//    (r6 vs r7); sim atomics are memory-side (WRITE 65.8MB invariant).
//  - single gemm dispatch vs 2x half: -26 us (r6 vs r5).
//  - loss NSUB=4 (544 blk) ~= loss 136-blk serial-16; 1088-blk variant +8.
// ---------------------------------------------------------------------------

// ---------------------------------------------------------------------------
// Kernel 0: zero sim (16 MB). Separate dispatch (r5-verified -8.6 us vs
// folding into norm).
// ---------------------------------------------------------------------------
__global__ __launch_bounds__(512) void zero_sim_kernel(float* __restrict__ sim)
{
  ((f32x4*)sim)[(size_t)blockIdx.x * 512 + threadIdx.x] =
      (f32x4){0.f, 0.f, 0.f, 0.f};
}

// ---------------------------------------------------------------------------
// Kernel 1: per-row normalize -> fp8 e4m3 (x16) rn[2048][16384] in the
// block-permuted global layout; zero rsum/cnt (block 0 only).
// ---------------------------------------------------------------------------
__global__ __launch_bounds__(512) void norm_kernel(
    const float* __restrict__ emb_i, const float* __restrict__ emb_j,
    unsigned char* __restrict__ rn,
    float* __restrict__ rsum, unsigned int* __restrict__ cnt)
{
  const int b = blockIdx.x;
  const int t = threadIdx.x;
  const int c = t & 31;        // column group (4 cols)
  const int g = t >> 5;        // row group (8 rows), 0..15

  if (b == 0) {
    for (int k = t; k < NROW; k += 512) rsum[k] = 0.f;
    if (t == 0) *cnt = 0u;
  }

  const float* src = (b < B_SZ) ? (emb_i + (size_t)b * D_K)
                                : (emb_j + (size_t)(b - B_SZ) * D_K);

  f32x4 vals[8];
  f32x4 ss = (f32x4){0.f, 0.f, 0.f, 0.f};
#pragma unroll
  for (int mm = 0; mm < 8; ++mm) {
    f32x4 v = *(const f32x4*)(src + (size_t)(g * 8 + mm) * 128 + c * 4);
    vals[mm] = v;
    ss += v * v;
  }

  __shared__ f32x4 part[16][32];
  part[g][c] = ss;
  __syncthreads();
  f32x4 css = part[0][c];
#pragma unroll
  for (int gg = 1; gg < 16; ++gg) css += part[gg][c];

  f32x4 mcn, colz2;
#pragma unroll
  for (int k = 0; k < 4; ++k) {
    mcn[k] = fmaxf(sqrtf(css[k]), 1e-12f);
    colz2[k] = css[k] / (mcn[k] * mcn[k]);
  }
  float s = colz2[0] + colz2[1] + colz2[2] + colz2[3];
#pragma unroll
  for (int off = 1; off < 64; off <<= 1) s += __shfl_xor(s, off);
  const float rowfac = fmaxf(sqrtf(0.5f * s), 1e-8f);

  f32x4 scale;
#pragma unroll
  for (int k = 0; k < 4; ++k) scale[k] = 16.0f / (mcn[k] * rowfac);

  unsigned char* dst = rn + (size_t)b * D_K;
  const int wsel = (b >> 1) & 3;
#pragma unroll
  for (int mm = 0; mm < 8; ++mm) {
    f32x4 sv = vals[mm] * scale;
    int p = 0;
    p = __builtin_amdgcn_cvt_pk_fp8_f32(sv[0], sv[1], p, false);
    p = __builtin_amdgcn_cvt_pk_fp8_f32(sv[2], sv[3], p, true);
    // original k-byte index of this int: k = (g*8+mm)*128 + c*4
    const int k = (g * 8 + mm) * 128 + c * 4;
    // permute within the 64B segment: q=(k>>3)&3, h=(k>>5)&1
    const int nk = (k & ~63) | ((((k >> 3) & 3) ^ wsel) << 4)
                 | (((k >> 5) & 1) << 3) | (k & 7);
    *(int*)(dst + nk) = p;
  }
}

// ---------------------------------------------------------------------------
// Kernel 2: sim(upper) += rn @ rn^T. fp8 MFMA, 128x128 tile, BK=128,
// r0/r6's PROVEN drain structure + zero-conflict layout. SINGLE dispatch,
// grid (SPLIT, NPAIR) = 1088 blocks: XCD = linear%8 = K-segment owner ->
// each XCD's 4MB rn K-slice is L2-resident (FETCH 16.4MB; the r7 swap gave
// 152MB and +8us). Block co-residency (~3/CU) hides the per-iter vmcnt(0)
// drain (m114); explicit 2-phase pipelines measured slower (r1/r2/r3).
// ---------------------------------------------------------------------------
__global__ __launch_bounds__(256) void gemm_sim_kernel(
    const unsigned char* __restrict__ rn, float* __restrict__ sim)
{
  int idx = blockIdx.y, tI = 0, rem = NTILE;
  while (idx >= rem) { idx -= rem; --rem; ++tI; }
  const int tJ = tI + idx;
  const bool diag = (tI == tJ);

  const int kBase = blockIdx.x * KSEG;
  const int t    = threadIdx.x;
  const int lane = t & 63;
  const int wave = t >> 6;
  const int wm = wave >> 1, wn = wave & 1;
  const int quad = lane >> 4, col = lane & 15;

  __shared__ __align__(16) unsigned char As[2][128 * 64];  // plane p = K-seg p
  __shared__ __align__(16) unsigned char Bs[2][128 * 64];

  // staging: instr (j,p) stages rows 64j..64j+63, segment p.
  // thread t -> row 64j+(t>>2), stored 16B chunk t&3 -> LDS plane p,
  // j*4096 + t*16 (lane-linear as global_load_lds requires).
  const int srow = t >> 2;
  const unsigned char* aGb = rn + (size_t)(tI * 128 + srow) * D_K + kBase + (t & 3) * 16;
  const unsigned char* bGb = rn + (size_t)(tJ * 128 + srow) * D_K + kBase + (t & 3) * 16;

  f32x4 acc[4][4];
#pragma unroll
  for (int mi = 0; mi < 4; ++mi)
#pragma unroll
    for (int ni = 0; ni < 4; ++ni)
      acc[mi][ni] = (f32x4){0.f, 0.f, 0.f, 0.f};

  // fragment-read 16B block: quad ^ ((row>>1)&3); row bits 1..2 come from col
  const int rblk = (quad ^ ((col >> 1) & 3)) * 16;

  for (int k0 = 0; k0 < KSEG; k0 += 128) {
    __syncthreads();   // previous compute done -> safe to overwrite
#pragma unroll
    for (int j = 0; j < 2; ++j)
#pragma unroll
      for (int p = 0; p < 2; ++p) {
        async16(aGb + (size_t)(64 * j) * D_K + k0 + p * 64,
                &As[p][j * 4096 + t * 16]);
        async16(bGb + (size_t)(64 * j) * D_K + k0 + p * 64,
                &Bs[p][j * 4096 + t * 16]);
      }
    __syncthreads();   // compiler emits vmcnt(0) drain before barrier

#pragma unroll
    for (int hh = 0; hh < 2; ++hh) {
      // one b128 per (row-fragment, segment): halves are k-steps 2hh, 2hh+1
      i64x2 av[4], bv[4];
#pragma unroll
      for (int mi = 0; mi < 4; ++mi)
        av[mi] = *(const i64x2*)(&As[hh][(wm * 64 + mi * 16 + col) * 64 + rblk]);
#pragma unroll
      for (int ni = 0; ni < 4; ++ni)
        bv[ni] = *(const i64x2*)(&Bs[hh][(wn * 64 + ni * 16 + col) * 64 + rblk]);

#pragma unroll
      for (int mi = 0; mi < 4; ++mi)
#pragma unroll
        for (int ni = 0; ni < 4; ++ni)
          acc[mi][ni] = __builtin_amdgcn_mfma_f32_16x16x32_fp8_fp8(
              av[mi][0], bv[ni][0], acc[mi][ni], 0, 0, 0);
#pragma unroll
      for (int mi = 0; mi < 4; ++mi)
#pragma unroll
        for (int ni = 0; ni < 4; ++ni)
          acc[mi][ni] = __builtin_amdgcn_mfma_f32_16x16x32_fp8_fp8(
              av[mi][1], bv[ni][1], acc[mi][ni], 0, 0, 0);
    }
  }

  // C/D layout: col=lane&15, row=quad*4+reg. Diag tiles: only j >= i stored.
  const int iB = tI * 128 + wm * 64;
  const int jB = tJ * 128 + wn * 64;
#pragma unroll
  for (int mi = 0; mi < 4; ++mi) {
#pragma unroll
    for (int reg = 0; reg < 4; ++reg) {
      const int i = iB + mi * 16 + quad * 4 + reg;
#pragma unroll
      for (int ni = 0; ni < 4; ++ni) {
        const int j = jB + ni * 16 + col;
        if (!diag || j >= i)
          atomicAdd(&sim[(size_t)i * NROW + j], acc[mi][ni][reg]);
      }
    }
  }
}

// ---------------------------------------------------------------------------
// Kernel 3: tile exp-sum (upper tiles, symmetric scatter) + fused finalize.
// NSUB=4 sub-blocks per tile -> 544 blocks, 4 serial steps (r7: ~= 136-blk
// serial-16 variant, -1us).
// ---------------------------------------------------------------------------
__global__ __launch_bounds__(256) void loss_tile_kernel(
    const float* __restrict__ sim, float* __restrict__ rsum,
    unsigned int* __restrict__ cnt, float* __restrict__ out)
{
  int idx = blockIdx.y, tI = 0, rem = NTILE;
  while (idx >= rem) { idx -= rem; --rem; ++tI; }
  const int tJ = tI + idx;
  const bool diag = (tI == tJ);

  const int t   = threadIdx.x;
  const int w   = t >> 6;
  const int l   = t & 63;
  const int hf  = l >> 5;
  const int sub = l & 31;
  const int jb  = tJ * 128 + sub * 4;
  const int rB  = blockIdx.x * 32;     // row sub-block within tile

  float ca[4] = {0.f, 0.f, 0.f, 0.f};

#pragma unroll
  for (int step = 0; step < 4; ++step) {
    const int r  = w * 8 + step * 2 + hf;          // 0..31
    const int gi = tI * 128 + rB + r;
    f32x4 v = *(const f32x4*)(sim + (size_t)gi * NROW + jb);
    float e[4];
#pragma unroll
    for (int k = 0; k < 4; ++k) {
      e[k] = __expf(TEMP_SIM * v[k]);
      if (diag && (jb + k <= gi)) e[k] = 0.f;
      ca[k] += e[k];
    }
    float rp = e[0] + e[1] + e[2] + e[3];
#pragma unroll
    for (int off = 1; off < 32; off <<= 1) rp += __shfl_xor(rp, off);
    if (sub == 0) atomicAdd(&rsum[gi], rp);
  }

  __shared__ float colacc[8][128];
#pragma unroll
  for (int k = 0; k < 4; ++k) colacc[w * 2 + hf][sub * 4 + k] = ca[k];
  __syncthreads();
  if (t < 128) {
    float s = 0.f;
#pragma unroll
    for (int q = 0; q < 8; ++q) s += colacc[q][t];
    atomicAdd(&rsum[tJ * 128 + t], s);
  }

  __syncthreads();
  __shared__ bool last;
  if (t == 0) {
    __threadfence();
    last = (atomicAdd(cnt, 1u) == NPT - 1);
  }
  __syncthreads();
  if (!last) return;

  float s = 0.f;
  for (int i = t; i < NROW; i += 256) {
    const int jp = (i < B_SZ) ? i + B_SZ : i - B_SZ;
    const float pos = (jp >= i) ? sim[(size_t)i * NROW + jp]
                                : sim[(size_t)jp * NROW + i];
    const float rs = atomicAdd(&rsum[i], 0.f);
    s += logf(rs) - TEMP_SIM * pos;
  }
#pragma unroll
  for (int off = 1; off < 64; off <<= 1) s += __shfl_xor(s, off);
  __shared__ float r[4];
  if ((t & 63) == 0) r[t >> 6] = s;
  __syncthreads();
  if (t == 0) out[0] = (r[0] + r[1] + r[2] + r[3]) * (1.0f / NROW);
}

extern "C" void kernel_launch(void* const* d_in, const int* in_sizes, int n_in,
                              void* d_out, int out_size, void* d_ws, size_t ws_size,
                              hipStream_t stream) {
  const float* emb_i = (const float*)d_in[0];
  const float* emb_j = (const float*)d_in[1];
  float* out = (float*)d_out;

  char* ws = (char*)d_ws;
  unsigned char* rn = (unsigned char*)ws;                 // 32 MB (fp8)
  float* sim  = (float*)(ws + (size_t)NROW * D_K);        // 16 MB
  float* rsum = sim + (size_t)NROW * NROW;                // 8 KB
  unsigned int* cnt = (unsigned int*)(rsum + NROW);

  zero_sim_kernel<<<dim3(2048), dim3(512), 0, stream>>>(sim);
  norm_kernel<<<dim3(NROW), dim3(512), 0, stream>>>(emb_i, emb_j, rn, rsum, cnt);
  gemm_sim_kernel<<<dim3(SPLIT, NPAIR), dim3(256), 0, stream>>>(rn, sim);
  loss_tile_kernel<<<dim3(NSUB, NPAIR), dim3(256), 0, stream>>>(sim, rsum, cnt, out);
}

// Round 9
// 252.759 us; speedup vs baseline: 1.0151x; 1.0151x over previous
//
#include <hip/hip_runtime.h>
#include <hip/hip_bf16.h>
#include <math.h>

#define B_SZ   1024
#define NROW   2048      // 2B
#define D_K    16384     // 128*128
#define SPLIT  8
#define KSEG   (D_K / SPLIT)   // 2048
#define NTILE  16
#define NPAIR  136
#define NSUB   4               // loss sub-blocks per tile (rows/32)
#define NPT    (NPAIR * NSUB)  // 544
// fp8 rows scaled by 16 each => sim holds 256 * true_sim.
#define TEMP_SIM (2.0f / 256.0f)

typedef float f32x4 __attribute__((ext_vector_type(4)));
typedef long  i64;
typedef long  i64x2 __attribute__((ext_vector_type(2)));

typedef __attribute__((address_space(1))) unsigned int GU32;
typedef __attribute__((address_space(3))) unsigned int LU32;

__device__ __forceinline__ void async16(const void* g, void* l) {
  __builtin_amdgcn_global_load_lds((GU32*)(g), (LU32*)(l), 16, 0, 0);
}

// ---------------------------------------------------------------------------
// rn GLOBAL layout (verified zero-conflict r3/r5/r6/r8): row r is split into
// 64B K-segments. Subchunk s (k-bytes [8s,8s+8)), q=s&3, h=s>>2 stored at
// byte (q ^ ((r>>1)&3))*16 + h*8. gemm stages each 64B segment as one LDS
// "plane" row (64B stride); fragment read = ONE ds_read_b128 per
// (row, segment) at row*64 + (quad^((col>>1)&3))*16; halves = the two
// K=32 MFMA operands. SQ_LDS_BANK_CONFLICT == 0 measured.
//
// CLEAN ledger (same-config pairs only; cross-round noise +-4us):
//  - zero fused into norm vs separate dispatch: -5us (r7 vs r8 rest).
//    [r7's claim of the opposite was noise-fitting, refuted by r8.]
//  - gemm grid (SPLIT,NPAIR) vs (NPAIR,SPLIT): -8us, FETCH 16.4 vs 152MB.
//  - single gemm dispatch vs 2x half: -26us (r6 vs r5).
//  - loss NSUB=4 vs 136-block serial-16: -1us (noise; keep NSUB=4 for
//    mechanism: 2.1 vs 0.53 blocks/CU).
//  - sim atomics are memory-side write-through (WRITE 65.8MB invariant
//    under XCD co-location) -- no L2-locality lever exists for them.
//  - 2-phase pipelines: 3 attempts all slower (occupancy loss dominates;
//    m233: simple-loop ceiling ~40% MfmaUtil; 8-phase needs a grid our
//    36 pair-tiles can't fill).
// ---------------------------------------------------------------------------

// ---------------------------------------------------------------------------
// Kernel 1: per-row normalize -> fp8 e4m3 (x16) rn[2048][16384] in the
// block-permuted global layout; zero sim/rsum/cnt (fused: r7 vs r8 = -5us).
// ---------------------------------------------------------------------------
__global__ __launch_bounds__(512) void norm_kernel(
    const float* __restrict__ emb_i, const float* __restrict__ emb_j,
    unsigned char* __restrict__ rn, float* __restrict__ sim,
    float* __restrict__ rsum, unsigned int* __restrict__ cnt)
{
  const int b = blockIdx.x;
  const int t = threadIdx.x;
  const int c = t & 31;        // column group (4 cols)
  const int g = t >> 5;        // row group (8 rows), 0..15

  ((f32x4*)sim)[(size_t)b * 512 + t] = (f32x4){0.f, 0.f, 0.f, 0.f};
  if (b == 0) {
    for (int k = t; k < NROW; k += 512) rsum[k] = 0.f;
    if (t == 0) *cnt = 0u;
  }

  const float* src = (b < B_SZ) ? (emb_i + (size_t)b * D_K)
                                : (emb_j + (size_t)(b - B_SZ) * D_K);

  f32x4 vals[8];
  f32x4 ss = (f32x4){0.f, 0.f, 0.f, 0.f};
#pragma unroll
  for (int mm = 0; mm < 8; ++mm) {
    f32x4 v = *(const f32x4*)(src + (size_t)(g * 8 + mm) * 128 + c * 4);
    vals[mm] = v;
    ss += v * v;
  }

  __shared__ f32x4 part[16][32];
  part[g][c] = ss;
  __syncthreads();
  f32x4 css = part[0][c];
#pragma unroll
  for (int gg = 1; gg < 16; ++gg) css += part[gg][c];

  f32x4 mcn, colz2;
#pragma unroll
  for (int k = 0; k < 4; ++k) {
    mcn[k] = fmaxf(sqrtf(css[k]), 1e-12f);
    colz2[k] = css[k] / (mcn[k] * mcn[k]);
  }
  float s = colz2[0] + colz2[1] + colz2[2] + colz2[3];
#pragma unroll
  for (int off = 1; off < 64; off <<= 1) s += __shfl_xor(s, off);
  const float rowfac = fmaxf(sqrtf(0.5f * s), 1e-8f);

  f32x4 scale;
#pragma unroll
  for (int k = 0; k < 4; ++k) scale[k] = 16.0f / (mcn[k] * rowfac);

  unsigned char* dst = rn + (size_t)b * D_K;
  const int wsel = (b >> 1) & 3;
#pragma unroll
  for (int mm = 0; mm < 8; ++mm) {
    f32x4 sv = vals[mm] * scale;
    int p = 0;
    p = __builtin_amdgcn_cvt_pk_fp8_f32(sv[0], sv[1], p, false);
    p = __builtin_amdgcn_cvt_pk_fp8_f32(sv[2], sv[3], p, true);
    // original k-byte index of this int: k = (g*8+mm)*128 + c*4
    const int k = (g * 8 + mm) * 128 + c * 4;
    // permute within the 64B segment: q=(k>>3)&3, h=(k>>5)&1
    const int nk = (k & ~63) | ((((k >> 3) & 3) ^ wsel) << 4)
                 | (((k >> 5) & 1) << 3) | (k & 7);
    *(int*)(dst + nk) = p;
  }
}

// ---------------------------------------------------------------------------
// Kernel 2: sim(upper) += rn @ rn^T. fp8 MFMA, 128x128 tile, BK=128,
// proven drain structure (sync / 8x global_load_lds / sync / 64 MFMA,
// 16 iters) + zero-conflict layout. SINGLE dispatch, grid (SPLIT, NPAIR) =
// 1088 blocks: XCD = linear%8 = K-segment owner -> each XCD's 4MB rn
// K-slice is L2-resident (FETCH 16.4MB). Block co-residency hides the
// per-iter vmcnt(0) drain (m114); explicit pipelines measured slower x3.
// 4-round-stable at 87-92us (cross-container noise +-2-4us).
// ---------------------------------------------------------------------------
__global__ __launch_bounds__(256) void gemm_sim_kernel(
    const unsigned char* __restrict__ rn, float* __restrict__ sim)
{
  int idx = blockIdx.y, tI = 0, rem = NTILE;
  while (idx >= rem) { idx -= rem; --rem; ++tI; }
  const int tJ = tI + idx;
  const bool diag = (tI == tJ);

  const int kBase = blockIdx.x * KSEG;
  const int t    = threadIdx.x;
  const int lane = t & 63;
  const int wave = t >> 6;
  const int wm = wave >> 1, wn = wave & 1;
  const int quad = lane >> 4, col = lane & 15;

  __shared__ __align__(16) unsigned char As[2][128 * 64];  // plane p = K-seg p
  __shared__ __align__(16) unsigned char Bs[2][128 * 64];

  // staging: instr (j,p) stages rows 64j..64j+63, segment p.
  // thread t -> row 64j+(t>>2), stored 16B chunk t&3 -> LDS plane p,
  // j*4096 + t*16 (lane-linear as global_load_lds requires).
  const int srow = t >> 2;
  const unsigned char* aGb = rn + (size_t)(tI * 128 + srow) * D_K + kBase + (t & 3) * 16;
  const unsigned char* bGb = rn + (size_t)(tJ * 128 + srow) * D_K + kBase + (t & 3) * 16;

  f32x4 acc[4][4];
#pragma unroll
  for (int mi = 0; mi < 4; ++mi)
#pragma unroll
    for (int ni = 0; ni < 4; ++ni)
      acc[mi][ni] = (f32x4){0.f, 0.f, 0.f, 0.f};

  // fragment-read 16B block: quad ^ ((row>>1)&3); row bits 1..2 come from col
  const int rblk = (quad ^ ((col >> 1) & 3)) * 16;

  for (int k0 = 0; k0 < KSEG; k0 += 128) {
    __syncthreads();   // previous compute done -> safe to overwrite
#pragma unroll
    for (int j = 0; j < 2; ++j)
#pragma unroll
      for (int p = 0; p < 2; ++p) {
        async16(aGb + (size_t)(64 * j) * D_K + k0 + p * 64,
                &As[p][j * 4096 + t * 16]);
        async16(bGb + (size_t)(64 * j) * D_K + k0 + p * 64,
                &Bs[p][j * 4096 + t * 16]);
      }
    __syncthreads();   // compiler emits vmcnt(0) drain before barrier

#pragma unroll
    for (int hh = 0; hh < 2; ++hh) {
      // one b128 per (row-fragment, segment): halves are k-steps 2hh, 2hh+1
      i64x2 av[4], bv[4];
#pragma unroll
      for (int mi = 0; mi < 4; ++mi)
        av[mi] = *(const i64x2*)(&As[hh][(wm * 64 + mi * 16 + col) * 64 + rblk]);
#pragma unroll
      for (int ni = 0; ni < 4; ++ni)
        bv[ni] = *(const i64x2*)(&Bs[hh][(wn * 64 + ni * 16 + col) * 64 + rblk]);

#pragma unroll
      for (int mi = 0; mi < 4; ++mi)
#pragma unroll
        for (int ni = 0; ni < 4; ++ni)
          acc[mi][ni] = __builtin_amdgcn_mfma_f32_16x16x32_fp8_fp8(
              av[mi][0], bv[ni][0], acc[mi][ni], 0, 0, 0);
#pragma unroll
      for (int mi = 0; mi < 4; ++mi)
#pragma unroll
        for (int ni = 0; ni < 4; ++ni)
          acc[mi][ni] = __builtin_amdgcn_mfma_f32_16x16x32_fp8_fp8(
              av[mi][1], bv[ni][1], acc[mi][ni], 0, 0, 0);
    }
  }

  // C/D layout: col=lane&15, row=quad*4+reg. Diag tiles: only j >= i stored.
  const int iB = tI * 128 + wm * 64;
  const int jB = tJ * 128 + wn * 64;
#pragma unroll
  for (int mi = 0; mi < 4; ++mi) {
#pragma unroll
    for (int reg = 0; reg < 4; ++reg) {
      const int i = iB + mi * 16 + quad * 4 + reg;
#pragma unroll
      for (int ni = 0; ni < 4; ++ni) {
        const int j = jB + ni * 16 + col;
        if (!diag || j >= i)
          atomicAdd(&sim[(size_t)i * NROW + j], acc[mi][ni][reg]);
      }
    }
  }
}

// ---------------------------------------------------------------------------
// Kernel 3: tile exp-sum (upper tiles, symmetric scatter) + fused finalize.
// NSUB=4 sub-blocks per tile -> 544 blocks (2.1/CU), 4 serial steps.
// ---------------------------------------------------------------------------
__global__ __launch_bounds__(256) void loss_tile_kernel(
    const float* __restrict__ sim, float* __restrict__ rsum,
    unsigned int* __restrict__ cnt, float* __restrict__ out)
{
  int idx = blockIdx.y, tI = 0, rem = NTILE;
  while (idx >= rem) { idx -= rem; --rem; ++tI; }
  const int tJ = tI + idx;
  const bool diag = (tI == tJ);

  const int t   = threadIdx.x;
  const int w   = t >> 6;
  const int l   = t & 63;
  const int hf  = l >> 5;
  const int sub = l & 31;
  const int jb  = tJ * 128 + sub * 4;
  const int rB  = blockIdx.x * 32;     // row sub-block within tile

  float ca[4] = {0.f, 0.f, 0.f, 0.f};

#pragma unroll
  for (int step = 0; step < 4; ++step) {
    const int r  = w * 8 + step * 2 + hf;          // 0..31
    const int gi = tI * 128 + rB + r;
    f32x4 v = *(const f32x4*)(sim + (size_t)gi * NROW + jb);
    float e[4];
#pragma unroll
    for (int k = 0; k < 4; ++k) {
      e[k] = __expf(TEMP_SIM * v[k]);
      if (diag && (jb + k <= gi)) e[k] = 0.f;
      ca[k] += e[k];
    }
    float rp = e[0] + e[1] + e[2] + e[3];
#pragma unroll
    for (int off = 1; off < 32; off <<= 1) rp += __shfl_xor(rp, off);
    if (sub == 0) atomicAdd(&rsum[gi], rp);
  }

  __shared__ float colacc[8][128];
#pragma unroll
  for (int k = 0; k < 4; ++k) colacc[w * 2 + hf][sub * 4 + k] = ca[k];
  __syncthreads();
  if (t < 128) {
    float s = 0.f;
#pragma unroll
    for (int q = 0; q < 8; ++q) s += colacc[q][t];
    atomicAdd(&rsum[tJ * 128 + t], s);
  }

  __syncthreads();
  __shared__ bool last;
  if (t == 0) {
    __threadfence();
    last = (atomicAdd(cnt, 1u) == NPT - 1);
  }
  __syncthreads();
  if (!last) return;

  float s = 0.f;
  for (int i = t; i < NROW; i += 256) {
    const int jp = (i < B_SZ) ? i + B_SZ : i - B_SZ;
    const float pos = (jp >= i) ? sim[(size_t)i * NROW + jp]
                                : sim[(size_t)jp * NROW + i];
    const float rs = atomicAdd(&rsum[i], 0.f);
    s += logf(rs) - TEMP_SIM * pos;
  }
#pragma unroll
  for (int off = 1; off < 64; off <<= 1) s += __shfl_xor(s, off);
  __shared__ float r[4];
  if ((t & 63) == 0) r[t >> 6] = s;
  __syncthreads();
  if (t == 0) out[0] = (r[0] + r[1] + r[2] + r[3]) * (1.0f / NROW);
}

extern "C" void kernel_launch(void* const* d_in, const int* in_sizes, int n_in,
                              void* d_out, int out_size, void* d_ws, size_t ws_size,
                              hipStream_t stream) {
  const float* emb_i = (const float*)d_in[0];
  const float* emb_j = (const float*)d_in[1];
  float* out = (float*)d_out;

  char* ws = (char*)d_ws;
  unsigned char* rn = (unsigned char*)ws;                 // 32 MB (fp8)
  float* sim  = (float*)(ws + (size_t)NROW * D_K);        // 16 MB
  float* rsum = sim + (size_t)NROW * NROW;                // 8 KB
  unsigned int* cnt = (unsigned int*)(rsum + NROW);

  norm_kernel<<<dim3(NROW), dim3(512), 0, stream>>>(emb_i, emb_j, rn, sim, rsum, cnt);
  gemm_sim_kernel<<<dim3(SPLIT, NPAIR), dim3(256), 0, stream>>>(rn, sim);
  loss_tile_kernel<<<dim3(NSUB, NPAIR), dim3(256), 0, stream>>>(sim, rsum, cnt, out);
}

// Round 11
// 252.590 us; speedup vs baseline: 1.0158x; 1.0007x over previous
//
#include <hip/hip_runtime.h>
#include <hip/hip_bf16.h>
#include <math.h>

#define B_SZ   1024
#define NROW   2048      // 2B
#define D_K    16384     // 128*128
#define SPLIT  8
#define KSEG   (D_K / SPLIT)   // 2048
#define NTILE  16
#define NPAIR  136
#define NSUB   4               // loss sub-blocks per tile (rows/32)
#define NPT    (NPAIR * NSUB)  // 544
// fp8 rows scaled by 16 each => sim holds 256 * true_sim.
#define TEMP_SIM (2.0f / 256.0f)

typedef float f32x4 __attribute__((ext_vector_type(4)));
typedef long  i64;
typedef long  i64x2 __attribute__((ext_vector_type(2)));

typedef __attribute__((address_space(1))) unsigned int GU32;
typedef __attribute__((address_space(3))) unsigned int LU32;

__device__ __forceinline__ void async16(const void* g, void* l) {
  __builtin_amdgcn_global_load_lds((GU32*)(g), (LU32*)(l), 16, 0, 0);
}

// ---------------------------------------------------------------------------
// rn GLOBAL layout (verified zero-conflict r3/r5/r6/r8/r9): row r is split
// into 64B K-segments. Subchunk s (k-bytes [8s,8s+8)), q=s&3, h=s>>2 stored
// at byte (q ^ ((r>>1)&3))*16 + h*8. gemm stages each 64B segment as one LDS
// "plane" row (64B stride); fragment read = ONE ds_read_b128 per
// (row, segment) at row*64 + (quad^((col>>1)&3))*16; halves = the two
// K=32 MFMA operands. SQ_LDS_BANK_CONFLICT == 0 measured.
//
// CLEAN ledger (same-config pairs only; cross-container noise +-4us):
//  - gemm 2-barrier drain structure: 4-round stable 87-92us, MfmaUtil ~32%
//    (the ~37%-class structural ceiling). Worse: 2-phase x3 (104/128/114),
//    grid swap (+8, FETCH 16->152MB), dispatch split (+26).
//  - sim atomics are memory-side write-through (WRITE 65.8MB invariant);
//    no L2-locality lever exists for them.
//  - zero fused into norm ~= split (conflicting +-5us reads across r7/r8;
//    keep fused).
//  - loss NSUB=4 == 136-blk serial-16 within 1us.
//  - norm store path: r10 change -> 8B stores (this round's probe;
//    r10 bench was an infra failure, resubmitted unchanged like r4).
// ---------------------------------------------------------------------------

// ---------------------------------------------------------------------------
// Kernel 1: per-row normalize -> fp8 e4m3 (x16) rn[2048][16384] in the
// block-permuted global layout; zero sim/rsum/cnt.
// r10 restructure: thread (g,c) owns 4 rows x 8 consecutive floats, so each
// (row, c) pair produces one FULL 8B subchunk -> one 8B store (was 8x 4B
// scalar stores/thread). Loads stay 2x f32x4 per sub-row. Reduce is a
// 2-stage LDS fold (32 -> 8 -> 1). Wave covers 4 row-groups x 16 col-groups
// -> each column counted 4x in the wave reduce: rowfac = sqrt(0.25*s).
// ---------------------------------------------------------------------------
__global__ __launch_bounds__(512) void norm_kernel(
    const float* __restrict__ emb_i, const float* __restrict__ emb_j,
    unsigned char* __restrict__ rn, float* __restrict__ sim,
    float* __restrict__ rsum, unsigned int* __restrict__ cnt)
{
  const int b = blockIdx.x;
  const int t = threadIdx.x;
  const int c = t & 15;        // column group (8 cols), 0..15
  const int g = t >> 4;        // row group (4 rows), 0..31

  ((f32x4*)sim)[(size_t)b * 512 + t] = (f32x4){0.f, 0.f, 0.f, 0.f};
  if (b == 0) {
    for (int k = t; k < NROW; k += 512) rsum[k] = 0.f;
    if (t == 0) *cnt = 0u;
  }

  const float* src = (b < B_SZ) ? (emb_i + (size_t)b * D_K)
                                : (emb_j + (size_t)(b - B_SZ) * D_K);

  f32x4 vlo[4], vhi[4];
  f32x4 sslo = (f32x4){0.f, 0.f, 0.f, 0.f};
  f32x4 sshi = (f32x4){0.f, 0.f, 0.f, 0.f};
#pragma unroll
  for (int mm = 0; mm < 4; ++mm) {
    const float* p = src + (size_t)(g * 4 + mm) * 128 + c * 8;
    f32x4 a = *(const f32x4*)p;
    f32x4 d = *(const f32x4*)(p + 4);
    vlo[mm] = a; vhi[mm] = d;
    sslo += a * a; sshi += d * d;
  }

  // column sums: 2-stage fold 32 -> 8 -> 1
  __shared__ f32x4 plo[32][16], phi[32][16];   // 16 KB
  plo[g][c] = sslo; phi[g][c] = sshi;
  __syncthreads();
  if (g < 8) {
    f32x4 alo = plo[g][c] + plo[g + 8][c] + plo[g + 16][c] + plo[g + 24][c];
    f32x4 ahi = phi[g][c] + phi[g + 8][c] + phi[g + 16][c] + phi[g + 24][c];
    plo[g][c] = alo; phi[g][c] = ahi;
  }
  __syncthreads();
  f32x4 clo = plo[0][c], chi = phi[0][c];
#pragma unroll
  for (int gg = 1; gg < 8; ++gg) { clo += plo[gg][c]; chi += phi[gg][c]; }

  f32x4 mlo, mhi, zlo, zhi;
#pragma unroll
  for (int k = 0; k < 4; ++k) {
    mlo[k] = fmaxf(sqrtf(clo[k]), 1e-12f);
    zlo[k] = clo[k] / (mlo[k] * mlo[k]);
    mhi[k] = fmaxf(sqrtf(chi[k]), 1e-12f);
    zhi[k] = chi[k] / (mhi[k] * mhi[k]);
  }
  float s = zlo[0] + zlo[1] + zlo[2] + zlo[3]
          + zhi[0] + zhi[1] + zhi[2] + zhi[3];
#pragma unroll
  for (int off = 1; off < 64; off <<= 1) s += __shfl_xor(s, off);
  const float rowfac = fmaxf(sqrtf(0.25f * s), 1e-8f);

  f32x4 sclo, schi;
#pragma unroll
  for (int k = 0; k < 4; ++k) {
    sclo[k] = 16.0f / (mlo[k] * rowfac);
    schi[k] = 16.0f / (mhi[k] * rowfac);
  }

  // store: one 8B subchunk per (sub-row): k = rr*128 + c*8 ->
  // dst byte = rr*128 + (c>>3)*64 + (((c&3)^wsel)<<4) + ((c>>2)&1)*8
  unsigned char* dst = rn + (size_t)b * D_K;
  const int wsel = (b >> 1) & 3;
  const int segoff = (c >> 3) * 64 + (((c & 3) ^ wsel) << 4) + ((c >> 2) & 1) * 8;
#pragma unroll
  for (int mm = 0; mm < 4; ++mm) {
    f32x4 a = vlo[mm] * sclo;
    f32x4 d = vhi[mm] * schi;
    int p0 = 0, p1 = 0;
    p0 = __builtin_amdgcn_cvt_pk_fp8_f32(a[0], a[1], p0, false);
    p0 = __builtin_amdgcn_cvt_pk_fp8_f32(a[2], a[3], p0, true);
    p1 = __builtin_amdgcn_cvt_pk_fp8_f32(d[0], d[1], p1, false);
    p1 = __builtin_amdgcn_cvt_pk_fp8_f32(d[2], d[3], p1, true);
    const long w = ((long)(unsigned int)p1 << 32) | (unsigned int)p0;
    *(long*)(dst + (size_t)(g * 4 + mm) * 128 + segoff) = w;
  }
}

// ---------------------------------------------------------------------------
// Kernel 2: sim(upper) += rn @ rn^T. fp8 MFMA, 128x128 tile, BK=128,
// proven drain structure (sync / 8x global_load_lds / sync / 128 MFMA,
// 16 iters) + zero-conflict layout. SINGLE dispatch, grid (SPLIT, NPAIR) =
// 1088 blocks: XCD = linear%8 = K-segment owner -> each XCD's 4MB rn
// K-slice is L2-resident (FETCH 16.4MB). Block co-residency (~4.25/CU)
// hides the per-iter vmcnt(0) drain (m114). BYTE-IDENTICAL to r9.
// ---------------------------------------------------------------------------
__global__ __launch_bounds__(256) void gemm_sim_kernel(
    const unsigned char* __restrict__ rn, float* __restrict__ sim)
{
  int idx = blockIdx.y, tI = 0, rem = NTILE;
  while (idx >= rem) { idx -= rem; --rem; ++tI; }
  const int tJ = tI + idx;
  const bool diag = (tI == tJ);

  const int kBase = blockIdx.x * KSEG;
  const int t    = threadIdx.x;
  const int lane = t & 63;
  const int wave = t >> 6;
  const int wm = wave >> 1, wn = wave & 1;
  const int quad = lane >> 4, col = lane & 15;

  __shared__ __align__(16) unsigned char As[2][128 * 64];  // plane p = K-seg p
  __shared__ __align__(16) unsigned char Bs[2][128 * 64];

  // staging: instr (j,p) stages rows 64j..64j+63, segment p.
  // thread t -> row 64j+(t>>2), stored 16B chunk t&3 -> LDS plane p,
  // j*4096 + t*16 (lane-linear as global_load_lds requires).
  const int srow = t >> 2;
  const unsigned char* aGb = rn + (size_t)(tI * 128 + srow) * D_K + kBase + (t & 3) * 16;
  const unsigned char* bGb = rn + (size_t)(tJ * 128 + srow) * D_K + kBase + (t & 3) * 16;

  f32x4 acc[4][4];
#pragma unroll
  for (int mi = 0; mi < 4; ++mi)
#pragma unroll
    for (int ni = 0; ni < 4; ++ni)
      acc[mi][ni] = (f32x4){0.f, 0.f, 0.f, 0.f};

  // fragment-read 16B block: quad ^ ((row>>1)&3); row bits 1..2 come from col
  const int rblk = (quad ^ ((col >> 1) & 3)) * 16;

  for (int k0 = 0; k0 < KSEG; k0 += 128) {
    __syncthreads();   // previous compute done -> safe to overwrite
#pragma unroll
    for (int j = 0; j < 2; ++j)
#pragma unroll
      for (int p = 0; p < 2; ++p) {
        async16(aGb + (size_t)(64 * j) * D_K + k0 + p * 64,
                &As[p][j * 4096 + t * 16]);
        async16(bGb + (size_t)(64 * j) * D_K + k0 + p * 64,
                &Bs[p][j * 4096 + t * 16]);
      }
    __syncthreads();   // compiler emits vmcnt(0) drain before barrier

#pragma unroll
    for (int hh = 0; hh < 2; ++hh) {
      // one b128 per (row-fragment, segment): halves are k-steps 2hh, 2hh+1
      i64x2 av[4], bv[4];
#pragma unroll
      for (int mi = 0; mi < 4; ++mi)
        av[mi] = *(const i64x2*)(&As[hh][(wm * 64 + mi * 16 + col) * 64 + rblk]);
#pragma unroll
      for (int ni = 0; ni < 4; ++ni)
        bv[ni] = *(const i64x2*)(&Bs[hh][(wn * 64 + ni * 16 + col) * 64 + rblk]);

#pragma unroll
      for (int mi = 0; mi < 4; ++mi)
#pragma unroll
        for (int ni = 0; ni < 4; ++ni)
          acc[mi][ni] = __builtin_amdgcn_mfma_f32_16x16x32_fp8_fp8(
              av[mi][0], bv[ni][0], acc[mi][ni], 0, 0, 0);
#pragma unroll
      for (int mi = 0; mi < 4; ++mi)
#pragma unroll
        for (int ni = 0; ni < 4; ++ni)
          acc[mi][ni] = __builtin_amdgcn_mfma_f32_16x16x32_fp8_fp8(
              av[mi][1], bv[ni][1], acc[mi][ni], 0, 0, 0);
    }
  }

  // C/D layout: col=lane&15, row=quad*4+reg. Diag tiles: only j >= i stored.
  const int iB = tI * 128 + wm * 64;
  const int jB = tJ * 128 + wn * 64;
#pragma unroll
  for (int mi = 0; mi < 4; ++mi) {
#pragma unroll
    for (int reg = 0; reg < 4; ++reg) {
      const int i = iB + mi * 16 + quad * 4 + reg;
#pragma unroll
      for (int ni = 0; ni < 4; ++ni) {
        const int j = jB + ni * 16 + col;
        if (!diag || j >= i)
          atomicAdd(&sim[(size_t)i * NROW + j], acc[mi][ni][reg]);
      }
    }
  }
}

// ---------------------------------------------------------------------------
// Kernel 3: tile exp-sum (upper tiles, symmetric scatter) + fused finalize.
// NSUB=4 sub-blocks per tile -> 544 blocks (2.1/CU), 4 serial steps.
// BYTE-IDENTICAL to r9.
// ---------------------------------------------------------------------------
__global__ __launch_bounds__(256) void loss_tile_kernel(
    const float* __restrict__ sim, float* __restrict__ rsum,
    unsigned int* __restrict__ cnt, float* __restrict__ out)
{
  int idx = blockIdx.y, tI = 0, rem = NTILE;
  while (idx >= rem) { idx -= rem; --rem; ++tI; }
  const int tJ = tI + idx;
  const bool diag = (tI == tJ);

  const int t   = threadIdx.x;
  const int w   = t >> 6;
  const int l   = t & 63;
  const int hf  = l >> 5;
  const int sub = l & 31;
  const int jb  = tJ * 128 + sub * 4;
  const int rB  = blockIdx.x * 32;     // row sub-block within tile

  float ca[4] = {0.f, 0.f, 0.f, 0.f};

#pragma unroll
  for (int step = 0; step < 4; ++step) {
    const int r  = w * 8 + step * 2 + hf;          // 0..31
    const int gi = tI * 128 + rB + r;
    f32x4 v = *(const f32x4*)(sim + (size_t)gi * NROW + jb);
    float e[4];
#pragma unroll
    for (int k = 0; k < 4; ++k) {
      e[k] = __expf(TEMP_SIM * v[k]);
      if (diag && (jb + k <= gi)) e[k] = 0.f;
      ca[k] += e[k];
    }
    float rp = e[0] + e[1] + e[2] + e[3];
#pragma unroll
    for (int off = 1; off < 32; off <<= 1) rp += __shfl_xor(rp, off);
    if (sub == 0) atomicAdd(&rsum[gi], rp);
  }

  __shared__ float colacc[8][128];
#pragma unroll
  for (int k = 0; k < 4; ++k) colacc[w * 2 + hf][sub * 4 + k] = ca[k];
  __syncthreads();
  if (t < 128) {
    float s = 0.f;
#pragma unroll
    for (int q = 0; q < 8; ++q) s += colacc[q][t];
    atomicAdd(&rsum[tJ * 128 + t], s);
  }

  __syncthreads();
  __shared__ bool last;
  if (t == 0) {
    __threadfence();
    last = (atomicAdd(cnt, 1u) == NPT - 1);
  }
  __syncthreads();
  if (!last) return;

  float s = 0.f;
  for (int i = t; i < NROW; i += 256) {
    const int jp = (i < B_SZ) ? i + B_SZ : i - B_SZ;
    const float pos = (jp >= i) ? sim[(size_t)i * NROW + jp]
                                : sim[(size_t)jp * NROW + i];
    const float rs = atomicAdd(&rsum[i], 0.f);
    s += logf(rs) - TEMP_SIM * pos;
  }
#pragma unroll
  for (int off = 1; off < 64; off <<= 1) s += __shfl_xor(s, off);
  __shared__ float r[4];
  if ((t & 63) == 0) r[t >> 6] = s;
  __syncthreads();
  if (t == 0) out[0] = (r[0] + r[1] + r[2] + r[3]) * (1.0f / NROW);
}

extern "C" void kernel_launch(void* const* d_in, const int* in_sizes, int n_in,
                              void* d_out, int out_size, void* d_ws, size_t ws_size,
                              hipStream_t stream) {
  const float* emb_i = (const float*)d_in[0];
  const float* emb_j = (const float*)d_in[1];
  float* out = (float*)d_out;

  char* ws = (char*)d_ws;
  unsigned char* rn = (unsigned char*)ws;                 // 32 MB (fp8)
  float* sim  = (float*)(ws + (size_t)NROW * D_K);        // 16 MB
  float* rsum = sim + (size_t)NROW * NROW;                // 8 KB
  unsigned int* cnt = (unsigned int*)(rsum + NROW);

  norm_kernel<<<dim3(NROW), dim3(512), 0, stream>>>(emb_i, emb_j, rn, sim, rsum, cnt);
  gemm_sim_kernel<<<dim3(SPLIT, NPAIR), dim3(256), 0, stream>>>(rn, sim);
  loss_tile_kernel<<<dim3(NSUB, NPAIR), dim3(256), 0, stream>>>(sim, rsum, cnt, out);
}